// Round 14
// baseline (474.749 us; speedup 1.0000x reference)
//
#include <hip/hip_runtime.h>
#include <hip/hip_bf16.h>
#include <math.h>

#define TSEQ 2048
#define HEADS 16
#define HSZ 64
#define CDIM 1024
#define MROWS 4096   // B*T
#define CHUNK 64
#define NCHUNK (TSEQ/CHUNK)   // 32
#define NBH 32                // B*HEADS
#define LSTR 68               // LDS row stride (shorts) for 64-wide bf16 mats
#define K2 2048               // doubled K for shared [x|xx] GEMMs
#define KS2 160               // stacked second-stage K (64+32+64)

typedef short bf16x8 __attribute__((ext_vector_type(8)));
typedef short bf16x4 __attribute__((ext_vector_type(4)));
typedef float f32x4 __attribute__((ext_vector_type(4)));

typedef __attribute__((address_space(3))) unsigned int lds_u32;
typedef const __attribute__((address_space(1))) unsigned int glb_u32;

__device__ __forceinline__ float sigf(float x) { return 1.0f / (1.0f + expf(-x)); }

__device__ __forceinline__ short to_bf16(float f) {
    __hip_bfloat16 h = __float2bfloat16(f);
    return *reinterpret_cast<short*>(&h);
}
__device__ __forceinline__ float bf2f(short s) {
    unsigned int u = ((unsigned int)(unsigned short)s) << 16;
    return __uint_as_float(u);
}

// ---------------------------------------------------------------------------
// A-builder: axbf [4096][2048] bf16 = [ x | shift(x)-x ]
// ---------------------------------------------------------------------------
__global__ __launch_bounds__(256)
void mix_make(const float* __restrict__ x, short* __restrict__ ax)
{
    const int m = blockIdx.x;
    const int cc = threadIdx.x * 4;
    const float4 xv = *(const float4*)(x + (size_t)m*CDIM + cc);
    float4 xp = make_float4(0.f, 0.f, 0.f, 0.f);
    if ((m & (TSEQ-1)) != 0) xp = *(const float4*)(x + (size_t)(m-1)*CDIM + cc);
    bf16x4 a, b;
    a[0] = to_bf16(xv.x); a[1] = to_bf16(xv.y);
    a[2] = to_bf16(xv.z); a[3] = to_bf16(xv.w);
    b[0] = to_bf16(xp.x - xv.x); b[1] = to_bf16(xp.y - xv.y);
    b[2] = to_bf16(xp.z - xv.z); b[3] = to_bf16(xp.w - xv.w);
    *(bf16x4*)(ax + (size_t)m*K2 + cc)        = a;
    *(bf16x4*)(ax + (size_t)m*K2 + CDIM + cc) = b;
}

// ---------------------------------------------------------------------------
// Plain transpose+cvt:  W [K,N] f32 -> Wt [N,K] bf16
// ---------------------------------------------------------------------------
__global__ __launch_bounds__(256)
void transpose_cvt(const float* __restrict__ W, short* __restrict__ Wt,
                   const int K, const int N)
{
    __shared__ float t[32][33];
    const int k0 = blockIdx.y * 32, n0 = blockIdx.x * 32;
    const int lx = threadIdx.x & 31, ly = threadIdx.x >> 5;
#pragma unroll
    for (int i = 0; i < 4; ++i)
        t[ly + i*8][lx] = W[(size_t)(k0 + ly + i*8)*N + n0 + lx];
    __syncthreads();
#pragma unroll
    for (int i = 0; i < 4; ++i)
        Wt[(size_t)(n0 + ly + i*8)*K + k0 + lx] = to_bf16(t[lx][ly + i*8]);
}

// ---------------------------------------------------------------------------
// Merged scaled transposes for the three big projections (z selects r/k/v)
// ---------------------------------------------------------------------------
__global__ __launch_bounds__(256)
void trans_rkv(const float* __restrict__ Wr, const float* __restrict__ Wk,
               const float* __restrict__ Wv,
               const float* __restrict__ xr, const float* __restrict__ xk,
               const float* __restrict__ xv, short* __restrict__ Brkv)
{
    const int z = blockIdx.z;
    const float* W   = (z == 0) ? Wr : (z == 1) ? Wk : Wv;
    const float* mix = (z == 0) ? xr : (z == 1) ? xk : xv;
    short* Wt = Brkv + (size_t)z*CDIM*K2;

    __shared__ float t[32][33];
    const int k0 = blockIdx.y * 32, n0 = blockIdx.x * 32;
    const int lx = threadIdx.x & 31, ly = threadIdx.x >> 5;
#pragma unroll
    for (int i = 0; i < 4; ++i)
        t[ly + i*8][lx] = W[(size_t)(k0 + ly + i*8)*CDIM + n0 + lx];
    __syncthreads();
    const float mv = mix[k0 + lx];
#pragma unroll
    for (int i = 0; i < 4; ++i) {
        const float w = t[lx][ly + i*8];
        short* base = Wt + (size_t)(n0 + ly + i*8)*K2 + k0 + lx;
        base[0]    = to_bf16(w);
        base[CDIM] = to_bf16(mv * w);
    }
}

// ---------------------------------------------------------------------------
// Merged scaled transposes for the small first stages
// ---------------------------------------------------------------------------
__global__ __launch_bounds__(256)
void trans_sm(const float* __restrict__ w1, const float* __restrict__ v1,
              const float* __restrict__ a1, const float* __restrict__ g1,
              const float* __restrict__ xw, const float* __restrict__ xv,
              const float* __restrict__ xa, const float* __restrict__ xg,
              short* __restrict__ Bsm)
{
    const int z = blockIdx.z;
    const float* W; const float* mix; int N, rowoff;
    if (z == 0)      { W = w1; mix = xw; N = 64;  rowoff = 0; }
    else if (z == 1) { W = v1; mix = xv; N = 32;  rowoff = 64; }
    else if (z == 2) { W = a1; mix = xa; N = 64;  rowoff = 96; }
    else             { W = g1; mix = xg; N = 128; rowoff = 160; }
    const int n0 = blockIdx.x * 32;
    if (n0 >= N) return;
    short* Wt = Bsm + (size_t)rowoff*K2;

    __shared__ float t[32][33];
    const int k0 = blockIdx.y * 32;
    const int lx = threadIdx.x & 31, ly = threadIdx.x >> 5;
#pragma unroll
    for (int i = 0; i < 4; ++i)
        t[ly + i*8][lx] = W[(size_t)(k0 + ly + i*8)*N + n0 + lx];
    __syncthreads();
    const float mv = mix[k0 + lx];
#pragma unroll
    for (int i = 0; i < 4; ++i) {
        const float w = t[lx][ly + i*8];
        short* base = Wt + (size_t)(n0 + ly + i*8)*K2 + k0 + lx;
        base[0]    = to_bf16(w);
        base[CDIM] = to_bf16(mv * w);
    }
}

// ---------------------------------------------------------------------------
// Stacked second-stage B builder: B2 [3072][160] bf16, zero-padded.
// ---------------------------------------------------------------------------
__global__ __launch_bounds__(256)
void trans_s2(const float* __restrict__ w2, const float* __restrict__ v2,
              const float* __restrict__ a2, short* __restrict__ B2)
{
    const int z  = blockIdx.z;
    const int y  = blockIdx.y;
    const int n0 = blockIdx.x * 32;
    const int kg0 = y * 32;
    const float* W = nullptr; int ks0 = 0;
    if (z == 0 && y < 2)       { W = w2; ks0 = kg0; }
    else if (z == 1 && y == 2) { W = v2; ks0 = kg0 - 64; }
    else if (z == 2 && y >= 3) { W = a2; ks0 = kg0 - 96; }

    __shared__ float t[32][33];
    const int lx = threadIdx.x & 31, ly = threadIdx.x >> 5;
    if (W) {
#pragma unroll
        for (int i = 0; i < 4; ++i)
            t[ly + i*8][lx] = W[(size_t)(ks0 + ly + i*8)*CDIM + n0 + lx];
        __syncthreads();
#pragma unroll
        for (int i = 0; i < 4; ++i)
            B2[(size_t)(z*1024 + n0 + ly + i*8)*KS2 + kg0 + lx] =
                to_bf16(t[lx][ly + i*8]);
    } else {
#pragma unroll
        for (int i = 0; i < 4; ++i)
            B2[(size_t)(z*1024 + n0 + ly + i*8)*KS2 + kg0 + lx] = 0;
    }
}

// ---------------------------------------------------------------------------
// bf16 MFMA GEMM with XCD-aware block swizzle (round-13 verified).
// ---------------------------------------------------------------------------
template<int BN, int MODE, bool GL>
__global__ __launch_bounds__(256)
void gemm_mfma(const short* __restrict__ A, const short* __restrict__ Bt,
               void* __restrict__ Cptr, const int M, const int N, const int K,
               void* __restrict__ C1, void* __restrict__ C2)
{
    constexpr int BM = 128, BK = 32;
    constexpr int ASTR = GL ? BK : (BK + 8);
    constexpr int NWC = (BN >= 128) ? 2 : 1;
    constexpr int NWR = 4 / NWC;
    constexpr int WM = BM / NWR;
    constexpr int WN = BN / NWC;
    constexpr int AM = WM / 16;
    constexpr int AN = WN / 16;

    __shared__ short As[BM * ASTR];
    __shared__ short Bs[BN * ASTR];

    const int tid  = threadIdx.x;
    int bxi = blockIdx.x, byi = blockIdx.y;
    {
        const int nwg  = gridDim.x * gridDim.y;
        if ((nwg & 7) == 0) {
            const int flat = byi * gridDim.x + bxi;
            const int q    = nwg >> 3;
            const int swz  = (flat & 7) * q + (flat >> 3);
            bxi = swz % gridDim.x;
            byi = swz / gridDim.x;
        }
    }
    const int bm   = byi * BM;
    const int bn   = bxi * BN;
    const int wid  = tid >> 6;
    const int lane = tid & 63;
    const int wr   = wid / NWC;
    const int wc   = wid % NWC;
    const int lrow = lane & 15;
    const int koff = (lane >> 4) * 8;

    f32x4 acc[AM][AN];
#pragma unroll
    for (int m = 0; m < AM; ++m)
#pragma unroll
        for (int n = 0; n < AN; ++n)
            acc[m][n] = (f32x4){0.f, 0.f, 0.f, 0.f};

    for (int k0 = 0; k0 < K; k0 += BK) {
        __syncthreads();
        if (GL) {
            const int rsub = lane >> 2;
            const int kb   = (lane & 3) * 8;
#pragma unroll
            for (int q = 0; q < 2; ++q) {
                const int seg = wid*2 + q;
                const short* gp = A + (size_t)(bm + seg*16 + rsub)*K + k0 + kb;
                __builtin_amdgcn_global_load_lds(
                    (glb_u32*)gp, (lds_u32*)(As + seg*512), 16, 0, 0);
            }
#pragma unroll
            for (int q = 0; q < 2; ++q) {
                const int seg = wid*2 + q;
                const short* gp = Bt + (size_t)(bn + seg*16 + rsub)*K + k0 + kb;
                __builtin_amdgcn_global_load_lds(
                    (glb_u32*)gp, (lds_u32*)(Bs + seg*512), 16, 0, 0);
            }
        } else {
#pragma unroll
            for (int p = 0; p < (BM*BK)/(256*8); ++p) {
                const int c = p*256 + tid;
                const int row = c >> 2;
                const int kc  = (c & 3) * 8;
                *(bf16x8*)&As[row*ASTR + kc] =
                    *(const bf16x8*)(A + (size_t)(bm+row)*K + k0 + kc);
            }
            constexpr int CHUNKS = (BN*BK)/8;
#pragma unroll
            for (int p = 0; p < (CHUNKS + 255)/256; ++p) {
                const int c = p*256 + tid;
                if ((CHUNKS & 255) == 0 || c < CHUNKS) {
                    const int col = c >> 2;
                    const int kc  = (c & 3) * 8;
                    *(bf16x8*)&Bs[col*ASTR + kc] =
                        *(const bf16x8*)(Bt + (size_t)(bn+col)*K + k0 + kc);
                }
            }
        }
        __syncthreads();

        bf16x8 af[AM], bfv[AN];
#pragma unroll
        for (int m = 0; m < AM; ++m)
            af[m] = *(const bf16x8*)&As[(wr*WM + m*16 + lrow)*ASTR + koff];
#pragma unroll
        for (int n = 0; n < AN; ++n)
            bfv[n] = *(const bf16x8*)&Bs[(wc*WN + n*16 + lrow)*ASTR + koff];
#pragma unroll
        for (int m = 0; m < AM; ++m)
#pragma unroll
            for (int n = 0; n < AN; ++n)
                acc[m][n] = __builtin_amdgcn_mfma_f32_16x16x32_bf16(
                    af[m], bfv[n], acc[m][n], 0, 0, 0);
    }

    const int r0 = (lane >> 4) * 4;
#pragma unroll
    for (int m = 0; m < AM; ++m) {
#pragma unroll
        for (int n = 0; n < AN; ++n) {
#pragma unroll
            for (int j = 0; j < 4; ++j) {
                const int row = bm + wr*WM + m*16 + r0 + j;
                const int col = bn + wc*WN + n*16 + lrow;
                float vv = acc[m][n][j];
                if (MODE == 0) {
                    ((float*)Cptr)[(size_t)row*N + col] = vv;
                } else if (MODE == 1) {
                    ((float*)Cptr)[(size_t)(col >> 10)*((size_t)MROWS*CDIM)
                                   + (size_t)row*CDIM + (col & 1023)] = vv;
                } else if (MODE == 2) {
                    short* o  = (short*)Cptr;                   // smA [M][160]
                    short* gh = o + (size_t)MROWS*KS2;          // ghbf [M][128]
                    if (col < 64)
                        o[(size_t)row*KS2 + col] = to_bf16(tanhf(vv));
                    else if (col < 160)
                        o[(size_t)row*KS2 + col] = to_bf16(vv);
                    else
                        gh[(size_t)row*128 + col - 160] = to_bf16(sigf(vv));
                } else {  // MODE 3
                    float* dst = (col < 1024) ? (float*)Cptr
                               : (col < 2048) ? (float*)C1 : (float*)C2;
                    dst[(size_t)row*CDIM + (col & 1023)] = vv;
                }
            }
        }
    }
}

// ---------------------------------------------------------------------------
// Per-row post-processing (round-6, verified)
// ---------------------------------------------------------------------------
__global__ __launch_bounds__(256)
void post_kernel(const float* __restrict__ tw, const float* __restrict__ vv,
                 const float* __restrict__ aa,
                 const float* __restrict__ w0, const float* __restrict__ v0p,
                 const float* __restrict__ a0p,
                 const float* __restrict__ k_k, const float* __restrict__ k_a,
                 const float* __restrict__ vfirst,
                 float* __restrict__ kio, float* __restrict__ vio,
                 float* __restrict__ dout, float* __restrict__ kkout,
                 float* __restrict__ bout)
{
    const int m  = blockIdx.x;
    const int c4 = threadIdx.x;
    const size_t o4 = (size_t)m*256 + c4;
    const int cc = c4*4;

    const float4 twv = ((const float4*)tw)[o4];
    const float4 vvv = ((const float4*)vv)[o4];
    const float4 aav = ((const float4*)aa)[o4];
    const float4 kv  = ((const float4*)kio)[o4];
    const float4 vv0 = ((const float4*)vio)[o4];
    const float4 vfv = ((const float4*)vfirst)[o4];
    const float4 w0v = *(const float4*)(w0 + cc);
    const float4 v0v = *(const float4*)(v0p + cc);
    const float4 a0v = *(const float4*)(a0p + cc);
    const float4 kkc = *(const float4*)(k_k + cc);
    const float4 kac = *(const float4*)(k_a + cc);

    float dec[4], vnew[4], av[4], kkr[4], knew[4];
    const float tws[4] = {twv.x, twv.y, twv.z, twv.w};
    const float vvs[4] = {vvv.x, vvv.y, vvv.z, vvv.w};
    const float aas[4] = {aav.x, aav.y, aav.z, aav.w};
    const float ks[4]  = {kv.x, kv.y, kv.z, kv.w};
    const float vs[4]  = {vv0.x, vv0.y, vv0.z, vv0.w};
    const float vfs[4] = {vfv.x, vfv.y, vfv.z, vfv.w};
    const float w0s[4] = {w0v.x, w0v.y, w0v.z, w0v.w};
    const float v0s[4] = {v0v.x, v0v.y, v0v.z, v0v.w};
    const float a0s[4] = {a0v.x, a0v.y, a0v.z, a0v.w};
    const float kks[4] = {kkc.x, kkc.y, kkc.z, kkc.w};
    const float kas[4] = {kac.x, kac.y, kac.z, kac.w};

    float ss = 0.f;
#pragma unroll
    for (int i = 0; i < 4; ++i) {
        dec[i]  = expf(-0.6065306597126334f * sigf(w0s[i] + tws[i]));
        const float sv = sigf(v0s[i] + vvs[i]);
        vnew[i] = vs[i] + (vfs[i] - vs[i]) * sv;
        av[i]   = sigf(a0s[i] + aas[i]);
        kkr[i]  = ks[i] * kks[i];
        knew[i] = ks[i] * (1.f + (av[i] - 1.f) * kas[i]);
        ss = fmaf(kkr[i], kkr[i], ss);
    }
#pragma unroll
    for (int mask = 1; mask < 16; mask <<= 1) ss += __shfl_xor(ss, mask);
    const float inv = fmaxf(rsqrtf(ss + 1e-12f), 1e-12f);

    float4 decv, vnv, knv, kkv4, bv4;
    decv.x = dec[0]; decv.y = dec[1]; decv.z = dec[2]; decv.w = dec[3];
    vnv.x = vnew[0]; vnv.y = vnew[1]; vnv.z = vnew[2]; vnv.w = vnew[3];
    knv.x = knew[0]; knv.y = knew[1]; knv.z = knew[2]; knv.w = knew[3];
    kkv4.x = kkr[0]*inv; kkv4.y = kkr[1]*inv; kkv4.z = kkr[2]*inv; kkv4.w = kkr[3]*inv;
    bv4.x = kkv4.x*av[0]; bv4.y = kkv4.y*av[1]; bv4.z = kkv4.z*av[2]; bv4.w = kkv4.w*av[3];

    ((float4*)dout)[o4]  = decv;
    ((float4*)vio)[o4]   = vnv;
    ((float4*)kio)[o4]   = knv;
    ((float4*)kkout)[o4] = kkv4;
    ((float4*)bout)[o4]  = bv4;
}

// ---------------------------------------------------------------------------
// Wave-slice helpers, 16-row x 64-col slice (4 col tiles).
// ---------------------------------------------------------------------------
__device__ __forceinline__ void zero4(f32x4 a[4]) {
#pragma unroll
    for (int n = 0; n < 4; ++n) a[n] = (f32x4){0.f, 0.f, 0.f, 0.f};
}

__device__ __forceinline__ void mm_nt_w(const short* __restrict__ Ab,
                                        const short* __restrict__ Bb,
                                        f32x4 acc[4], const int lane, const int woff)
{
    const int lrow = lane & 15;
    const int ko   = (lane >> 4) * 8;
#pragma unroll
    for (int kh = 0; kh < 2; ++kh) {
        const bf16x8 af = *(const bf16x8*)&Ab[(woff + lrow)*LSTR + kh*32 + ko];
        bf16x8 bv[4];
#pragma unroll
        for (int n = 0; n < 4; ++n)
            bv[n] = *(const bf16x8*)&Bb[(n*16 + lrow)*LSTR + kh*32 + ko];
#pragma unroll
        for (int n = 0; n < 4; ++n)
            acc[n] = __builtin_amdgcn_mfma_f32_16x16x32_bf16(af, bv[n], acc[n], 0, 0, 0);
    }
}

__device__ __forceinline__ void mm_nt_gf32_w(const short* __restrict__ Ab,
                                             const float* __restrict__ Bg,
                                             f32x4 acc[4], const int lane, const int woff)
{
    const int lrow = lane & 15;
    const int ko   = (lane >> 4) * 8;
#pragma unroll
    for (int kh = 0; kh < 2; ++kh) {
        const bf16x8 af = *(const bf16x8*)&Ab[(woff + lrow)*LSTR + kh*32 + ko];
#pragma unroll
        for (int n = 0; n < 4; ++n) {
            const float* p = Bg + (size_t)(n*16 + lrow)*64 + kh*32 + ko;
            const float4 u0 = *(const float4*)p;
            const float4 u1 = *(const float4*)(p + 4);
            bf16x8 bv;
            bv[0] = to_bf16(u0.x); bv[1] = to_bf16(u0.y);
            bv[2] = to_bf16(u0.z); bv[3] = to_bf16(u0.w);
            bv[4] = to_bf16(u1.x); bv[5] = to_bf16(u1.y);
            bv[6] = to_bf16(u1.z); bv[7] = to_bf16(u1.w);
            acc[n] = __builtin_amdgcn_mfma_f32_16x16x32_bf16(af, bv, acc[n], 0, 0, 0);
        }
    }
}

template<int MASK, bool WRN, bool WRT>
__device__ __forceinline__ void acc_store_w(const f32x4 acc[4],
                                            short* __restrict__ dst,
                                            short* __restrict__ dstT,
                                            const int lane, const int woff)
{
    const int r0 = (lane >> 4) * 4;
    const int c0 = lane & 15;
#pragma unroll
    for (int n = 0; n < 4; ++n)
#pragma unroll
        for (int j = 0; j < 4; ++j) {
            const int row = woff + r0 + j;
            const int col = n*16 + c0;
            float vv = acc[n][j];
            if (MASK == 1 && col >= row) vv = 0.f;
            if (MASK == 2 && col >  row) vv = 0.f;
            const short bv = to_bf16(vv);
            if (WRN) dst [row*LSTR + col] = bv;
            if (WRT) dstT[col*LSTR + row] = bv;
        }
}

__device__ __forceinline__ void acc_init_lds_w(f32x4 acc[4],
                                               const short* __restrict__ src,
                                               const int lane, const int woff)
{
    const int r0 = (lane >> 4) * 4;
    const int c0 = lane & 15;
#pragma unroll
    for (int n = 0; n < 4; ++n)
#pragma unroll
        for (int j = 0; j < 4; ++j)
            acc[n][j] = bf2f(src[(woff + r0 + j)*LSTR + n*16 + c0]);
}

__device__ __forceinline__ void acc_init_glb_w(f32x4 acc[4],
                                               const short* __restrict__ src,
                                               const int lane, const int woff)
{
    const int r0 = (lane >> 4) * 4;
    const int c0 = lane & 15;
#pragma unroll
    for (int n = 0; n < 4; ++n)
#pragma unroll
        for (int j = 0; j < 4; ++j)
            acc[n][j] = bf2f(src[(woff + r0 + j)*64 + n*16 + c0]);
}

// ---------------------------------------------------------------------------
// Scan pass 1, WY form, 4 waves/block, 6 LDS mats (53.5 KB -> 3 blocks/CU).
// BhT/KhT are re-materialized from global after the doubling (bit-identical
// values; Cb and N are dead by then). Math identical to round 13.
// ---------------------------------------------------------------------------
__global__ __launch_bounds__(256)
void scan_pass1_wy(const float* __restrict__ d, const float* __restrict__ k,
                   const float* __restrict__ v, const float* __restrict__ kk,
                   const float* __restrict__ bb,
                   float* __restrict__ Gbuf, float* __restrict__ Hbuf,
                   short* __restrict__ Yg, short* __restrict__ Ug)
{
    __shared__ short L[6*64*LSTR];
    __shared__ float wprod[4][64];
    __shared__ float cTl[64];
    short* A_  = L + 0*64*LSTR;  // Ah; later XiT
    short* B_  = L + 1*64*LSTR;  // Bh; later XjT
    short* K_  = L + 2*64*LSTR;  // Kh; later Cb; finally BhT
    short* V_  = L + 3*64*LSTR;  // Vt
    short* N_  = L + 4*64*LSTR;  // Nb; finally KhT
    short* NT_ = L + 5*64*LSTR;  // Nt

    const int chunk = blockIdx.x;
    const int bh = blockIdx.y;
    const int b = bh >> 4, h = bh & 15;
    const int tid = threadIdx.x;
    const int w = tid >> 6;
    const int lane = tid & 63;
    const int woff = w * 16;

    const size_t base = ((size_t)b*TSEQ + (size_t)chunk*CHUNK + woff)*CDIM + h*HSZ + lane;
    float lc[16];
    float s = 1.f;
#pragma unroll
    for (int t = 0; t < 16; ++t) { s *= d[base + (size_t)t*CDIM]; lc[t] = s; }
    wprod[w][lane] = s;
    __syncthreads();
    float pre = 1.f;
#pragma unroll
    for (int w2 = 0; w2 < 3; ++w2) if (w2 < w) pre *= wprod[w2][lane];
    if (w == 3) cTl[lane] = pre * s;

#pragma unroll
    for (int t = 0; t < 16; ++t) {
        const int tg = woff + t;
        const size_t off = base + (size_t)t*CDIM;
        const float run   = pre * lc[t];
        const float cprev = (t == 0) ? pre : (pre * lc[t-1]);
        const float ern   = 1.f / run;
        A_[tg*LSTR + lane] = to_bf16(-kk[off] * cprev);
        B_[tg*LSTR + lane] = to_bf16(bb[off] * ern);
        K_[tg*LSTR + lane] = to_bf16(k[off] * ern);
        V_[lane*LSTR + tg] = to_bf16(v[off]);
    }
    __syncthreads();

    f32x4 xj[4], xi[4], tmpN[4], tmpC[4];

    // Phase 1 (merged): N = stril(A B^T), C = stril(A K^T), xj = A rows
    zero4(tmpN);  mm_nt_w(A_, B_, tmpN, lane, woff);
    zero4(tmpC);  mm_nt_w(A_, K_, tmpC, lane, woff);
    acc_init_lds_w(xj, A_, lane, woff);
    __syncthreads();                       // reads of A_,B_,K_ complete
    acc_store_w<1, true, true >(tmpN, N_, NT_, lane, woff);
    acc_store_w<1, true, false>(tmpC, K_, nullptr, lane, woff);   // C -> K-space
    acc_store_w<0, false, true>(xj, nullptr, B_, lane, woff);     // XjT -> B-space
    __syncthreads();

    // Phase 2: xi = C V; XiT -> A-space
    zero4(xi);  mm_nt_w(K_, V_, xi, lane, woff);
    acc_store_w<0, false, true>(xi, nullptr, A_, lane, woff);
    __syncthreads();

    // Neumann doubling (exact: N^64 = 0)
#pragma unroll 1
    for (int rd = 0; rd < 6; ++rd) {
        mm_nt_w(N_, B_, xj, lane, woff);
        mm_nt_w(N_, A_, xi, lane, woff);
        if (rd < 5) { zero4(tmpN); mm_nt_w(N_, NT_, tmpN, lane, woff); }
        __syncthreads();
        acc_store_w<0, false, true>(xj, nullptr, B_, lane, woff);
        acc_store_w<0, false, true>(xi, nullptr, A_, lane, woff);
        if (rd < 5) acc_store_w<0, true, true>(tmpN, N_, NT_, lane, woff);
        __syncthreads();
    }

    const size_t mb = ((size_t)bh*NCHUNK + chunk)*HSZ*HSZ;
    const int r0 = (lane >> 4) * 4;
    const int c0 = lane & 15;

    // Y, U to global (bf16) for pass3-lite
#pragma unroll
    for (int n = 0; n < 4; ++n)
#pragma unroll
        for (int j = 0; j < 4; ++j) {
            const int row = woff + r0 + j;
            const int col = n*16 + c0;
            Yg[mb + row*64 + col] = to_bf16(xj[n][j]);
            Ug[mb + row*64 + col] = to_bf16(xi[n][j]);
        }

    // Re-materialize BhT -> K_ (Cb dead), KhT -> N_ (N dead); bit-identical
    // to the staged values (same inputs, same expression).
#pragma unroll
    for (int t = 0; t < 16; ++t) {
        const int tg = woff + t;
        const size_t off = base + (size_t)t*CDIM;
        const float ern = 1.f / (pre * lc[t]);
        K_[lane*LSTR + tg] = to_bf16(bb[off] * ern);
        N_[lane*LSTR + tg] = to_bf16(k[off]  * ern);
    }
    __syncthreads();

    float ctv[4];
#pragma unroll
    for (int n = 0; n < 4; ++n) ctv[n] = cTl[n*16 + c0];

    // G = (I + Y^T Bh) diag(cT)   [B_ = XjT, K_ = BhT]
    zero4(tmpN);  mm_nt_w(B_, K_, tmpN, lane, woff);
#pragma unroll
    for (int n = 0; n < 4; ++n)
#pragma unroll
        for (int j = 0; j < 4; ++j) {
            const int row = woff + r0 + j;
            const int col = n*16 + c0;
            const float id = (row == col) ? 1.f : 0.f;
            Gbuf[mb + (size_t)row*HSZ + col] = (tmpN[n][j] + id) * ctv[n];
        }

    // H = (U^T Bh + Vm^T Kh) diag(cT)   [A_ = XiT, K_ = BhT, N_ = KhT]
    zero4(tmpN);
    mm_nt_w(A_, K_, tmpN, lane, woff);
    mm_nt_w(V_, N_, tmpN, lane, woff);
#pragma unroll
    for (int n = 0; n < 4; ++n)
#pragma unroll
        for (int j = 0; j < 4; ++j) {
            const int row = woff + r0 + j;
            const int col = n*16 + c0;
            Hbuf[mb + (size_t)row*HSZ + col] = tmpN[n][j] * ctv[n];
        }
}

// ---------------------------------------------------------------------------
// Scan pass 2 (unchanged, verified)
// ---------------------------------------------------------------------------
__global__ __launch_bounds__(256)
void scan_pass2(const float* __restrict__ Gbuf, const float* __restrict__ Hbuf,
                float* __restrict__ S0buf)
{
    const int rg = blockIdx.x;
    const int bh = blockIdx.y;
    const int tid = threadIdx.x;
    const int il = tid & 15;
    const int q4 = tid >> 4;
    const int row = rg*16 + il;

    __shared__ float Gs[64][68];
    __shared__ float Ssh[16][68];

    float frag[4] = {0.f, 0.f, 0.f, 0.f};
    *(float4*)&Ssh[il][q4*4] = make_float4(0.f, 0.f, 0.f, 0.f);

    for (int c = 0; c < NCHUNK; ++c) {
        const size_t mbase = ((size_t)bh*NCHUNK + c)*HSZ*HSZ;
#pragma unroll
        for (int p = 0; p < 4; ++p) {
            const int f = tid*16 + p*4;
            const int rr = f >> 6, cc = f & 63;
            *(float4*)&Gs[rr][cc] = *(const float4*)(Gbuf + mbase + f);
        }
        *(float4*)(S0buf + mbase + (size_t)row*HSZ + q4*4) =
            make_float4(frag[0], frag[1], frag[2], frag[3]);
        __syncthreads();

        float4 hv = *(const float4*)(Hbuf + mbase + (size_t)row*HSZ + q4*4);
        float a0 = hv.x, a1 = hv.y, a2 = hv.z, a3 = hv.w;
#pragma unroll
        for (int j = 0; j < 64; ++j) {
            const float sj = Ssh[il][j];
            const float4 gv = *(const float4*)&Gs[j][q4*4];
            a0 = fmaf(sj, gv.x, a0);
            a1 = fmaf(sj, gv.y, a1);
            a2 = fmaf(sj, gv.z, a2);
            a3 = fmaf(sj, gv.w, a3);
        }
        __syncthreads();
        frag[0] = a0; frag[1] = a1; frag[2] = a2; frag[3] = a3;
        *(float4*)&Ssh[il][q4*4] = make_float4(a0, a1, a2, a3);
    }
}

// ---------------------------------------------------------------------------
// Scan pass 3 lite, 4 waves/block, 5 LDS mats (44.5 KB -> 3 blocks/CU).
// Wt/P1/P2 reuse Yn/B_/K_ after their readers complete. Math = round 13.
// ---------------------------------------------------------------------------
__global__ __launch_bounds__(256)
void scan_pass3_lite4(const float* __restrict__ r, const float* __restrict__ d,
                      const float* __restrict__ k, const float* __restrict__ v,
                      const float* __restrict__ bb,
                      const short* __restrict__ Yg, const short* __restrict__ Ug,
                      const float* __restrict__ S0buf, float* __restrict__ y)
{
    __shared__ short L[5*64*LSTR];
    __shared__ float wprod[4][64];
    short* R_  = L + 0*64*LSTR;  // Rh
    short* B_  = L + 1*64*LSTR;  // Bh; later P1
    short* K_  = L + 2*64*LSTR;  // Kh; later P2
    short* V_  = L + 3*64*LSTR;  // Vt
    short* Yn  = L + 4*64*LSTR;  // Y;  later Wt

    const int chunk = blockIdx.x;
    const int bh = blockIdx.y;
    const int b = bh >> 4, h = bh & 15;
    const int tid = threadIdx.x;
    const int w = tid >> 6;
    const int lane = tid & 63;
    const int woff = w * 16;
    const size_t mb = ((size_t)bh*NCHUNK + chunk)*HSZ*HSZ;

    const size_t base = ((size_t)b*TSEQ + (size_t)chunk*CHUNK + woff)*CDIM + h*HSZ + lane;
    float lc[16];
    float s = 1.f;
#pragma unroll
    for (int t = 0; t < 16; ++t) { s *= d[base + (size_t)t*CDIM]; lc[t] = s; }
    wprod[w][lane] = s;
    __syncthreads();
    float pre = 1.f;
#pragma unroll
    for (int w2 = 0; w2 < 3; ++w2) if (w2 < w) pre *= wprod[w2][lane];

#pragma unroll
    for (int t = 0; t < 16; ++t) {
        const int tg = woff + t;
        const size_t off = base + (size_t)t*CDIM;
        const float run = pre * lc[t];
        const float ern = 1.f / run;
        R_[tg*LSTR + lane] = to_bf16(r[off] * run);
        B_[tg*LSTR + lane] = to_bf16(bb[off] * ern);
        K_[tg*LSTR + lane] = to_bf16(k[off]  * ern);
        V_[lane*LSTR + tg] = to_bf16(v[off]);
    }
    {
        const int row = woff + (lane & 15);
        const int cb  = (lane >> 4) * 16;
        const short* yp = Yg + mb + (size_t)row*64 + cb;
        *(bf16x8*)&Yn[row*LSTR + cb]     = *(const bf16x8*)yp;
        *(bf16x8*)&Yn[row*LSTR + cb + 8] = *(const bf16x8*)(yp + 8);
    }
    __syncthreads();

    const float* S0g = S0buf + mb;
    f32x4 wv[4], p1[4], p2[4], o4[4];

    // Phase A: W = U + Y S0^T ; P1 = tril(Rh Bh^T) ; P2 = tril(Rh Kh^T)
    acc_init_glb_w(wv, Ug + mb, lane, woff);
    mm_nt_gf32_w(Yn, S0g, wv, lane, woff);
    zero4(p1);  mm_nt_w(R_, B_, p1, lane, woff);
    zero4(p2);  mm_nt_w(R_, K_, p2, lane, woff);
    __syncthreads();                       // all reads of Yn, B_, K_ done
    acc_store_w<0, false, true>(wv, nullptr, Yn, lane, woff);   // Wt -> Yn
    acc_store_w<2, true, false>(p1, B_, nullptr, lane, woff);   // P1 -> B_
    acc_store_w<2, true, false>(p2, K_, nullptr, lane, woff);   // P2 -> K_
    __syncthreads();

    // Phase B: Out = Rh S0^T + P1 W + P2 V
    zero4(o4);
    mm_nt_gf32_w(R_, S0g, o4, lane, woff);
    mm_nt_w(B_, Yn, o4, lane, woff);
    mm_nt_w(K_, V_, o4, lane, woff);

    const int r0 = (lane >> 4) * 4;
    const int c0 = lane & 15;
    float* yb = y + ((size_t)b*TSEQ + (size_t)chunk*CHUNK)*CDIM + h*HSZ;
#pragma unroll
    for (int n = 0; n < 4; ++n)
#pragma unroll
        for (int j = 0; j < 4; ++j)
            yb[(size_t)(woff + r0 + j)*CDIM + n*16 + c0] = o4[n][j];
}

// ---------------------------------------------------------------------------
// GroupNorm + rank-1 rwkv residual + *g; writes bf16 (y*g) for the Wo GEMM.
// ---------------------------------------------------------------------------
__global__ __launch_bounds__(1024)
void gn_kernel(const float* __restrict__ r, const float* __restrict__ k,
               const float* __restrict__ v, const float* __restrict__ g,
               const float* __restrict__ rk, const float* __restrict__ gamma,
               const float* __restrict__ beta, const float* __restrict__ y,
               short* __restrict__ ybf)
{
    const int m = blockIdx.x;
    const int c = threadIdx.x;
    const size_t o = (size_t)m*CDIM + c;
    const float yv = y[o];
    float s1 = yv, s2 = yv*yv;
#pragma unroll
    for (int mask = 1; mask < 64; mask <<= 1) {
        s1 += __shfl_xor(s1, mask);
        s2 += __shfl_xor(s2, mask);
    }
    const float mu  = s1 * (1.f/HSZ);
    const float var = s2 * (1.f/HSZ) - mu*mu;
    const float gn  = (yv - mu) * rsqrtf(var + 0.00064f) * gamma[c] + beta[c];

    float p = r[o] * k[o] * rk[c];
#pragma unroll
    for (int mask = 1; mask < 64; mask <<= 1) p += __shfl_xor(p, mask);

    ybf[o] = to_bf16((gn + p * v[o]) * g[o]);
}

// ---------------------------------------------------------------------------
extern "C" void kernel_launch(void* const* d_in, const int* in_sizes, int n_in,
                              void* d_out, int out_size, void* d_ws, size_t ws_size,
                              hipStream_t stream)
{
    const float* x      = (const float*)d_in[0];
    const float* vfirst = (const float*)d_in[1];
    const float* x_r = (const float*)d_in[2];
    const float* x_w = (const float*)d_in[3];
    const float* x_k = (const float*)d_in[4];
    const float* x_v = (const float*)d_in[5];
    const float* x_a = (const float*)d_in[6];
    const float* x_g = (const float*)d_in[7];
    const float* w0  = (const float*)d_in[8];
    const float* w1  = (const float*)d_in[9];
    const float* w2  = (const float*)d_in[10];
    const float* a0  = (const float*)d_in[11];
    const float* a1  = (const float*)d_in[12];
    const float* a2  = (const float*)d_in[13];
    const float* v0p = (const float*)d_in[14];
    const float* v1  = (const float*)d_in[15];
    const float* v2  = (const float*)d_in[16];
    const float* g1  = (const float*)d_in[17];
    const float* g2  = (const float*)d_in[18];
    const float* k_k = (const float*)d_in[19];
    const float* k_a = (const float*)d_in[20];
    const float* r_k = (const float*)d_in[21];
    const float* Wr  = (const float*)d_in[22];
    const float* Wk  = (const float*)d_in[23];
    const float* Wv  = (const float*)d_in[24];
    const float* Wo  = (const float*)d_in[25];
    const float* lng = (const float*)d_in[26];
    const float* lnb = (const float*)d_in[27];
    float* outp = (float*)d_out;

    float* ws = (float*)d_ws;
    const size_t BIG = (size_t)MROWS * CDIM;   // 4 Mi floats = 16 MB
    float* rbuf  = ws + 0*BIG;
    float* kbuf  = ws + 1*BIG;
    float* vbuf  = ws + 2*BIG;
    float* dbuf  = ws + 3*BIG;
    float* kkbuf = ws + 4*BIG;
    float* bbuf  = ws + 5*BIG;
    float* gbuf  = ws + 6*BIG;
    float* ybuf  = ws + 7*BIG;
    float* smbuf = ws + 8*BIG;
    short* smA   = (short*)smbuf;
    short* wT    = (short*)(smbuf + (size_t)MROWS*160/2);
    short* Brkv = wT;                                    // [3072][2048]
    short* Bsm  = Brkv + (size_t)3072*K2;                // [288][2048]
    short* WoT  = Bsm  + (size_t)288*K2;                 // [1024][1024]
    short* g2T  = WoT  + (size_t)CDIM*CDIM;              // [1024][128]
    short* axbf = g2T  + (size_t)CDIM*128;               // [4096][2048]
    short* Bsm2 = axbf + (size_t)MROWS*K2;               // [3072][160]

    short* Yg = axbf;
    short* Ug = axbf + (size_t)NBH*NCHUNK*HSZ*HSZ;

    float* twbuf = ybuf;
    float* vvbuf = gbuf;
    float* aabuf = outp;

    float* Gbuf  = ybuf;
    float* Hbuf  = gbuf;
    float* S0buf = outp;
    short* ybf   = (short*)dbuf;
    short* ghbf  = smA + (size_t)MROWS*KS2;

    const dim3 blk(256);

    mix_make<<<dim3(MROWS), blk, 0, stream>>>(x, axbf);
    trans_rkv<<<dim3(32, 32, 3), blk, 0, stream>>>(Wr, Wk, Wv, x_r, x_k, x_v, Brkv);
    trans_sm<<<dim3(4, 32, 4), blk, 0, stream>>>(w1, v1, a1, g1, x_w, x_v, x_a, x_g, Bsm);
    trans_s2<<<dim3(32, 5, 3), blk, 0, stream>>>(w2, v2, a2, Bsm2);
    transpose_cvt<<<dim3(CDIM/32, CDIM/32), blk, 0, stream>>>(Wo, WoT, CDIM, CDIM);
    transpose_cvt<<<dim3(CDIM/32, 128/32),  blk, 0, stream>>>(g2, g2T, 128, CDIM);

    gemm_mfma<128,1,true><<<dim3(3072/128, MROWS/128), blk, 0, stream>>>(
        axbf, Brkv, rbuf, MROWS, 3072, K2, nullptr, nullptr);
    gemm_mfma<32,2,false><<<dim3(288/32, MROWS/128), blk, 0, stream>>>(
        axbf, Bsm, smA, MROWS, 288, K2, nullptr, nullptr);
    gemm_mfma<128,3,false><<<dim3(3072/128, MROWS/128), blk, 0, stream>>>(
        smA, Bsm2, twbuf, MROWS, 3072, KS2, vvbuf, aabuf);

    post_kernel<<<dim3(MROWS), blk, 0, stream>>>(
        twbuf, vvbuf, aabuf, w0, v0p, a0, k_k, k_a, vfirst,
        kbuf, vbuf, dbuf, kkbuf, bbuf);

    scan_pass1_wy<<<dim3(NCHUNK, NBH), blk, 0, stream>>>(
        dbuf, kbuf, vbuf, kkbuf, bbuf, Gbuf, Hbuf, Yg, Ug);
    scan_pass2<<<dim3(4, NBH), blk, 0, stream>>>(Gbuf, Hbuf, S0buf);
    scan_pass3_lite4<<<dim3(NCHUNK, NBH), blk, 0, stream>>>(
        rbuf, dbuf, kbuf, vbuf, bbuf, Yg, Ug, S0buf, ybuf);

    gemm_mfma<128,0,false><<<dim3(CDIM/128, MROWS/128), blk, 0, stream>>>(
        ghbf, g2T, gbuf, MROWS, CDIM, 128, nullptr, nullptr);

    gn_kernel<<<dim3(MROWS), dim3(1024), 0, stream>>>(
        rbuf, kbuf, vbuf, gbuf, r_k, lng, lnb, ybuf, ybf);

    gemm_mfma<128,0,true><<<dim3(CDIM/128, MROWS/128), blk, 0, stream>>>(
        ybf, WoT, outp, MROWS, CDIM, CDIM, nullptr, nullptr);
}

// Round 15
// 439.012 us; speedup vs baseline: 1.0814x; 1.0814x over previous
//
#include <hip/hip_runtime.h>
#include <hip/hip_bf16.h>
#include <math.h>

#define TSEQ 2048
#define HEADS 16
#define HSZ 64
#define CDIM 1024
#define MROWS 4096   // B*T
#define CHUNK 64
#define NCHUNK (TSEQ/CHUNK)   // 32
#define NBH 32                // B*HEADS
#define LSTR 68               // LDS row stride (shorts) for 64-wide bf16 mats
#define K2 2048               // doubled K for shared [x|xx] GEMMs
#define KS2 160               // stacked second-stage K (64+32+64)

typedef short bf16x8 __attribute__((ext_vector_type(8)));
typedef short bf16x4 __attribute__((ext_vector_type(4)));
typedef float f32x4 __attribute__((ext_vector_type(4)));

typedef __attribute__((address_space(3))) unsigned int lds_u32;
typedef const __attribute__((address_space(1))) unsigned int glb_u32;

__device__ __forceinline__ float sigf(float x) { return 1.0f / (1.0f + expf(-x)); }

__device__ __forceinline__ short to_bf16(float f) {
    __hip_bfloat16 h = __float2bfloat16(f);
    return *reinterpret_cast<short*>(&h);
}
__device__ __forceinline__ float bf2f(short s) {
    unsigned int u = ((unsigned int)(unsigned short)s) << 16;
    return __uint_as_float(u);
}

// ---------------------------------------------------------------------------
// A-builder: axbf [4096][2048] bf16 = [ x | shift(x)-x ]
// ---------------------------------------------------------------------------
__global__ __launch_bounds__(256)
void mix_make(const float* __restrict__ x, short* __restrict__ ax)
{
    const int m = blockIdx.x;
    const int cc = threadIdx.x * 4;
    const float4 xv = *(const float4*)(x + (size_t)m*CDIM + cc);
    float4 xp = make_float4(0.f, 0.f, 0.f, 0.f);
    if ((m & (TSEQ-1)) != 0) xp = *(const float4*)(x + (size_t)(m-1)*CDIM + cc);
    bf16x4 a, b;
    a[0] = to_bf16(xv.x); a[1] = to_bf16(xv.y);
    a[2] = to_bf16(xv.z); a[3] = to_bf16(xv.w);
    b[0] = to_bf16(xp.x - xv.x); b[1] = to_bf16(xp.y - xv.y);
    b[2] = to_bf16(xp.z - xv.z); b[3] = to_bf16(xp.w - xv.w);
    *(bf16x4*)(ax + (size_t)m*K2 + cc)        = a;
    *(bf16x4*)(ax + (size_t)m*K2 + CDIM + cc) = b;
}

// ---------------------------------------------------------------------------
// Plain transpose+cvt:  W [K,N] f32 -> Wt [N,K] bf16
// ---------------------------------------------------------------------------
__global__ __launch_bounds__(256)
void transpose_cvt(const float* __restrict__ W, short* __restrict__ Wt,
                   const int K, const int N)
{
    __shared__ float t[32][33];
    const int k0 = blockIdx.y * 32, n0 = blockIdx.x * 32;
    const int lx = threadIdx.x & 31, ly = threadIdx.x >> 5;
#pragma unroll
    for (int i = 0; i < 4; ++i)
        t[ly + i*8][lx] = W[(size_t)(k0 + ly + i*8)*N + n0 + lx];
    __syncthreads();
#pragma unroll
    for (int i = 0; i < 4; ++i)
        Wt[(size_t)(n0 + ly + i*8)*K + k0 + lx] = to_bf16(t[lx][ly + i*8]);
}

// ---------------------------------------------------------------------------
// Merged scaled transposes for the three big projections (z selects r/k/v)
// ---------------------------------------------------------------------------
__global__ __launch_bounds__(256)
void trans_rkv(const float* __restrict__ Wr, const float* __restrict__ Wk,
               const float* __restrict__ Wv,
               const float* __restrict__ xr, const float* __restrict__ xk,
               const float* __restrict__ xv, short* __restrict__ Brkv)
{
    const int z = blockIdx.z;
    const float* W   = (z == 0) ? Wr : (z == 1) ? Wk : Wv;
    const float* mix = (z == 0) ? xr : (z == 1) ? xk : xv;
    short* Wt = Brkv + (size_t)z*CDIM*K2;

    __shared__ float t[32][33];
    const int k0 = blockIdx.y * 32, n0 = blockIdx.x * 32;
    const int lx = threadIdx.x & 31, ly = threadIdx.x >> 5;
#pragma unroll
    for (int i = 0; i < 4; ++i)
        t[ly + i*8][lx] = W[(size_t)(k0 + ly + i*8)*CDIM + n0 + lx];
    __syncthreads();
    const float mv = mix[k0 + lx];
#pragma unroll
    for (int i = 0; i < 4; ++i) {
        const float w = t[lx][ly + i*8];
        short* base = Wt + (size_t)(n0 + ly + i*8)*K2 + k0 + lx;
        base[0]    = to_bf16(w);
        base[CDIM] = to_bf16(mv * w);
    }
}

// ---------------------------------------------------------------------------
// Merged scaled transposes for the small first stages
// ---------------------------------------------------------------------------
__global__ __launch_bounds__(256)
void trans_sm(const float* __restrict__ w1, const float* __restrict__ v1,
              const float* __restrict__ a1, const float* __restrict__ g1,
              const float* __restrict__ xw, const float* __restrict__ xv,
              const float* __restrict__ xa, const float* __restrict__ xg,
              short* __restrict__ Bsm)
{
    const int z = blockIdx.z;
    const float* W; const float* mix; int N, rowoff;
    if (z == 0)      { W = w1; mix = xw; N = 64;  rowoff = 0; }
    else if (z == 1) { W = v1; mix = xv; N = 32;  rowoff = 64; }
    else if (z == 2) { W = a1; mix = xa; N = 64;  rowoff = 96; }
    else             { W = g1; mix = xg; N = 128; rowoff = 160; }
    const int n0 = blockIdx.x * 32;
    if (n0 >= N) return;
    short* Wt = Bsm + (size_t)rowoff*K2;

    __shared__ float t[32][33];
    const int k0 = blockIdx.y * 32;
    const int lx = threadIdx.x & 31, ly = threadIdx.x >> 5;
#pragma unroll
    for (int i = 0; i < 4; ++i)
        t[ly + i*8][lx] = W[(size_t)(k0 + ly + i*8)*N + n0 + lx];
    __syncthreads();
    const float mv = mix[k0 + lx];
#pragma unroll
    for (int i = 0; i < 4; ++i) {
        const float w = t[lx][ly + i*8];
        short* base = Wt + (size_t)(n0 + ly + i*8)*K2 + k0 + lx;
        base[0]    = to_bf16(w);
        base[CDIM] = to_bf16(mv * w);
    }
}

// ---------------------------------------------------------------------------
// Stacked second-stage B builder: B2 [3072][160] bf16, zero-padded.
// ---------------------------------------------------------------------------
__global__ __launch_bounds__(256)
void trans_s2(const float* __restrict__ w2, const float* __restrict__ v2,
              const float* __restrict__ a2, short* __restrict__ B2)
{
    const int z  = blockIdx.z;
    const int y  = blockIdx.y;
    const int n0 = blockIdx.x * 32;
    const int kg0 = y * 32;
    const float* W = nullptr; int ks0 = 0;
    if (z == 0 && y < 2)       { W = w2; ks0 = kg0; }
    else if (z == 1 && y == 2) { W = v2; ks0 = kg0 - 64; }
    else if (z == 2 && y >= 3) { W = a2; ks0 = kg0 - 96; }

    __shared__ float t[32][33];
    const int lx = threadIdx.x & 31, ly = threadIdx.x >> 5;
    if (W) {
#pragma unroll
        for (int i = 0; i < 4; ++i)
            t[ly + i*8][lx] = W[(size_t)(ks0 + ly + i*8)*CDIM + n0 + lx];
        __syncthreads();
#pragma unroll
        for (int i = 0; i < 4; ++i)
            B2[(size_t)(z*1024 + n0 + ly + i*8)*KS2 + kg0 + lx] =
                to_bf16(t[lx][ly + i*8]);
    } else {
#pragma unroll
        for (int i = 0; i < 4; ++i)
            B2[(size_t)(z*1024 + n0 + ly + i*8)*KS2 + kg0 + lx] = 0;
    }
}

// ---------------------------------------------------------------------------
// bf16 MFMA GEMM with XCD-aware block swizzle (round-13 verified).
// ---------------------------------------------------------------------------
template<int BN, int MODE, bool GL>
__global__ __launch_bounds__(256)
void gemm_mfma(const short* __restrict__ A, const short* __restrict__ Bt,
               void* __restrict__ Cptr, const int M, const int N, const int K,
               void* __restrict__ C1, void* __restrict__ C2)
{
    constexpr int BM = 128, BK = 32;
    constexpr int ASTR = GL ? BK : (BK + 8);
    constexpr int NWC = (BN >= 128) ? 2 : 1;
    constexpr int NWR = 4 / NWC;
    constexpr int WM = BM / NWR;
    constexpr int WN = BN / NWC;
    constexpr int AM = WM / 16;
    constexpr int AN = WN / 16;

    __shared__ short As[BM * ASTR];
    __shared__ short Bs[BN * ASTR];

    const int tid  = threadIdx.x;
    int bxi = blockIdx.x, byi = blockIdx.y;
    {
        const int nwg  = gridDim.x * gridDim.y;
        if ((nwg & 7) == 0) {
            const int flat = byi * gridDim.x + bxi;
            const int q    = nwg >> 3;
            const int swz  = (flat & 7) * q + (flat >> 3);
            bxi = swz % gridDim.x;
            byi = swz / gridDim.x;
        }
    }
    const int bm   = byi * BM;
    const int bn   = bxi * BN;
    const int wid  = tid >> 6;
    const int lane = tid & 63;
    const int wr   = wid / NWC;
    const int wc   = wid % NWC;
    const int lrow = lane & 15;
    const int koff = (lane >> 4) * 8;

    f32x4 acc[AM][AN];
#pragma unroll
    for (int m = 0; m < AM; ++m)
#pragma unroll
        for (int n = 0; n < AN; ++n)
            acc[m][n] = (f32x4){0.f, 0.f, 0.f, 0.f};

    for (int k0 = 0; k0 < K; k0 += BK) {
        __syncthreads();
        if (GL) {
            const int rsub = lane >> 2;
            const int kb   = (lane & 3) * 8;
#pragma unroll
            for (int q = 0; q < 2; ++q) {
                const int seg = wid*2 + q;
                const short* gp = A + (size_t)(bm + seg*16 + rsub)*K + k0 + kb;
                __builtin_amdgcn_global_load_lds(
                    (glb_u32*)gp, (lds_u32*)(As + seg*512), 16, 0, 0);
            }
#pragma unroll
            for (int q = 0; q < 2; ++q) {
                const int seg = wid*2 + q;
                const short* gp = Bt + (size_t)(bn + seg*16 + rsub)*K + k0 + kb;
                __builtin_amdgcn_global_load_lds(
                    (glb_u32*)gp, (lds_u32*)(Bs + seg*512), 16, 0, 0);
            }
        } else {
#pragma unroll
            for (int p = 0; p < (BM*BK)/(256*8); ++p) {
                const int c = p*256 + tid;
                const int row = c >> 2;
                const int kc  = (c & 3) * 8;
                *(bf16x8*)&As[row*ASTR + kc] =
                    *(const bf16x8*)(A + (size_t)(bm+row)*K + k0 + kc);
            }
            constexpr int CHUNKS = (BN*BK)/8;
#pragma unroll
            for (int p = 0; p < (CHUNKS + 255)/256; ++p) {
                const int c = p*256 + tid;
                if ((CHUNKS & 255) == 0 || c < CHUNKS) {
                    const int col = c >> 2;
                    const int kc  = (c & 3) * 8;
                    *(bf16x8*)&Bs[col*ASTR + kc] =
                        *(const bf16x8*)(Bt + (size_t)(bn+col)*K + k0 + kc);
                }
            }
        }
        __syncthreads();

        bf16x8 af[AM], bfv[AN];
#pragma unroll
        for (int m = 0; m < AM; ++m)
            af[m] = *(const bf16x8*)&As[(wr*WM + m*16 + lrow)*ASTR + koff];
#pragma unroll
        for (int n = 0; n < AN; ++n)
            bfv[n] = *(const bf16x8*)&Bs[(wc*WN + n*16 + lrow)*ASTR + koff];
#pragma unroll
        for (int m = 0; m < AM; ++m)
#pragma unroll
            for (int n = 0; n < AN; ++n)
                acc[m][n] = __builtin_amdgcn_mfma_f32_16x16x32_bf16(
                    af[m], bfv[n], acc[m][n], 0, 0, 0);
    }

    const int r0 = (lane >> 4) * 4;
#pragma unroll
    for (int m = 0; m < AM; ++m) {
#pragma unroll
        for (int n = 0; n < AN; ++n) {
#pragma unroll
            for (int j = 0; j < 4; ++j) {
                const int row = bm + wr*WM + m*16 + r0 + j;
                const int col = bn + wc*WN + n*16 + lrow;
                float vv = acc[m][n][j];
                if (MODE == 0) {
                    ((float*)Cptr)[(size_t)row*N + col] = vv;
                } else if (MODE == 1) {
                    ((float*)Cptr)[(size_t)(col >> 10)*((size_t)MROWS*CDIM)
                                   + (size_t)row*CDIM + (col & 1023)] = vv;
                } else if (MODE == 2) {
                    short* o  = (short*)Cptr;                   // smA [M][160]
                    short* gh = o + (size_t)MROWS*KS2;          // ghbf [M][128]
                    if (col < 64)
                        o[(size_t)row*KS2 + col] = to_bf16(tanhf(vv));
                    else if (col < 160)
                        o[(size_t)row*KS2 + col] = to_bf16(vv);
                    else
                        gh[(size_t)row*128 + col - 160] = to_bf16(sigf(vv));
                } else {  // MODE 3
                    float* dst = (col < 1024) ? (float*)Cptr
                               : (col < 2048) ? (float*)C1 : (float*)C2;
                    dst[(size_t)row*CDIM + (col & 1023)] = vv;
                }
            }
        }
    }
}

// ---------------------------------------------------------------------------
// Per-row post-processing (round-6, verified)
// ---------------------------------------------------------------------------
__global__ __launch_bounds__(256)
void post_kernel(const float* __restrict__ tw, const float* __restrict__ vv,
                 const float* __restrict__ aa,
                 const float* __restrict__ w0, const float* __restrict__ v0p,
                 const float* __restrict__ a0p,
                 const float* __restrict__ k_k, const float* __restrict__ k_a,
                 const float* __restrict__ vfirst,
                 float* __restrict__ kio, float* __restrict__ vio,
                 float* __restrict__ dout, float* __restrict__ kkout,
                 float* __restrict__ bout)
{
    const int m  = blockIdx.x;
    const int c4 = threadIdx.x;
    const size_t o4 = (size_t)m*256 + c4;
    const int cc = c4*4;

    const float4 twv = ((const float4*)tw)[o4];
    const float4 vvv = ((const float4*)vv)[o4];
    const float4 aav = ((const float4*)aa)[o4];
    const float4 kv  = ((const float4*)kio)[o4];
    const float4 vv0 = ((const float4*)vio)[o4];
    const float4 vfv = ((const float4*)vfirst)[o4];
    const float4 w0v = *(const float4*)(w0 + cc);
    const float4 v0v = *(const float4*)(v0p + cc);
    const float4 a0v = *(const float4*)(a0p + cc);
    const float4 kkc = *(const float4*)(k_k + cc);
    const float4 kac = *(const float4*)(k_a + cc);

    float dec[4], vnew[4], av[4], kkr[4], knew[4];
    const float tws[4] = {twv.x, twv.y, twv.z, twv.w};
    const float vvs[4] = {vvv.x, vvv.y, vvv.z, vvv.w};
    const float aas[4] = {aav.x, aav.y, aav.z, aav.w};
    const float ks[4]  = {kv.x, kv.y, kv.z, kv.w};
    const float vs[4]  = {vv0.x, vv0.y, vv0.z, vv0.w};
    const float vfs[4] = {vfv.x, vfv.y, vfv.z, vfv.w};
    const float w0s[4] = {w0v.x, w0v.y, w0v.z, w0v.w};
    const float v0s[4] = {v0v.x, v0v.y, v0v.z, v0v.w};
    const float a0s[4] = {a0v.x, a0v.y, a0v.z, a0v.w};
    const float kks[4] = {kkc.x, kkc.y, kkc.z, kkc.w};
    const float kas[4] = {kac.x, kac.y, kac.z, kac.w};

    float ss = 0.f;
#pragma unroll
    for (int i = 0; i < 4; ++i) {
        dec[i]  = expf(-0.6065306597126334f * sigf(w0s[i] + tws[i]));
        const float sv = sigf(v0s[i] + vvs[i]);
        vnew[i] = vs[i] + (vfs[i] - vs[i]) * sv;
        av[i]   = sigf(a0s[i] + aas[i]);
        kkr[i]  = ks[i] * kks[i];
        knew[i] = ks[i] * (1.f + (av[i] - 1.f) * kas[i]);
        ss = fmaf(kkr[i], kkr[i], ss);
    }
#pragma unroll
    for (int mask = 1; mask < 16; mask <<= 1) ss += __shfl_xor(ss, mask);
    const float inv = fmaxf(rsqrtf(ss + 1e-12f), 1e-12f);

    float4 decv, vnv, knv, kkv4, bv4;
    decv.x = dec[0]; decv.y = dec[1]; decv.z = dec[2]; decv.w = dec[3];
    vnv.x = vnew[0]; vnv.y = vnew[1]; vnv.z = vnew[2]; vnv.w = vnew[3];
    knv.x = knew[0]; knv.y = knew[1]; knv.z = knew[2]; knv.w = knew[3];
    kkv4.x = kkr[0]*inv; kkv4.y = kkr[1]*inv; kkv4.z = kkr[2]*inv; kkv4.w = kkr[3]*inv;
    bv4.x = kkv4.x*av[0]; bv4.y = kkv4.y*av[1]; bv4.z = kkv4.z*av[2]; bv4.w = kkv4.w*av[3];

    ((float4*)dout)[o4]  = decv;
    ((float4*)vio)[o4]   = vnv;
    ((float4*)kio)[o4]   = knv;
    ((float4*)kkout)[o4] = kkv4;
    ((float4*)bout)[o4]  = bv4;
}

// ---------------------------------------------------------------------------
// Wave-slice helpers, 16-row x 64-col slice (4 col tiles).
// ---------------------------------------------------------------------------
__device__ __forceinline__ void zero4(f32x4 a[4]) {
#pragma unroll
    for (int n = 0; n < 4; ++n) a[n] = (f32x4){0.f, 0.f, 0.f, 0.f};
}

__device__ __forceinline__ void mm_nt_w(const short* __restrict__ Ab,
                                        const short* __restrict__ Bb,
                                        f32x4 acc[4], const int lane, const int woff)
{
    const int lrow = lane & 15;
    const int ko   = (lane >> 4) * 8;
#pragma unroll
    for (int kh = 0; kh < 2; ++kh) {
        const bf16x8 af = *(const bf16x8*)&Ab[(woff + lrow)*LSTR + kh*32 + ko];
        bf16x8 bv[4];
#pragma unroll
        for (int n = 0; n < 4; ++n)
            bv[n] = *(const bf16x8*)&Bb[(n*16 + lrow)*LSTR + kh*32 + ko];
#pragma unroll
        for (int n = 0; n < 4; ++n)
            acc[n] = __builtin_amdgcn_mfma_f32_16x16x32_bf16(af, bv[n], acc[n], 0, 0, 0);
    }
}

__device__ __forceinline__ void mm_nt_gf32_w(const short* __restrict__ Ab,
                                             const float* __restrict__ Bg,
                                             f32x4 acc[4], const int lane, const int woff)
{
    const int lrow = lane & 15;
    const int ko   = (lane >> 4) * 8;
#pragma unroll
    for (int kh = 0; kh < 2; ++kh) {
        const bf16x8 af = *(const bf16x8*)&Ab[(woff + lrow)*LSTR + kh*32 + ko];
#pragma unroll
        for (int n = 0; n < 4; ++n) {
            const float* p = Bg + (size_t)(n*16 + lrow)*64 + kh*32 + ko;
            const float4 u0 = *(const float4*)p;
            const float4 u1 = *(const float4*)(p + 4);
            bf16x8 bv;
            bv[0] = to_bf16(u0.x); bv[1] = to_bf16(u0.y);
            bv[2] = to_bf16(u0.z); bv[3] = to_bf16(u0.w);
            bv[4] = to_bf16(u1.x); bv[5] = to_bf16(u1.y);
            bv[6] = to_bf16(u1.z); bv[7] = to_bf16(u1.w);
            acc[n] = __builtin_amdgcn_mfma_f32_16x16x32_bf16(af, bv, acc[n], 0, 0, 0);
        }
    }
}

template<int MASK, bool WRN, bool WRT>
__device__ __forceinline__ void acc_store_w(const f32x4 acc[4],
                                            short* __restrict__ dst,
                                            short* __restrict__ dstT,
                                            const int lane, const int woff)
{
    const int r0 = (lane >> 4) * 4;
    const int c0 = lane & 15;
#pragma unroll
    for (int n = 0; n < 4; ++n)
#pragma unroll
        for (int j = 0; j < 4; ++j) {
            const int row = woff + r0 + j;
            const int col = n*16 + c0;
            float vv = acc[n][j];
            if (MASK == 1 && col >= row) vv = 0.f;
            if (MASK == 2 && col >  row) vv = 0.f;
            const short bv = to_bf16(vv);
            if (WRN) dst [row*LSTR + col] = bv;
            if (WRT) dstT[col*LSTR + row] = bv;
        }
}

__device__ __forceinline__ void acc_init_lds_w(f32x4 acc[4],
                                               const short* __restrict__ src,
                                               const int lane, const int woff)
{
    const int r0 = (lane >> 4) * 4;
    const int c0 = lane & 15;
#pragma unroll
    for (int n = 0; n < 4; ++n)
#pragma unroll
        for (int j = 0; j < 4; ++j)
            acc[n][j] = bf2f(src[(woff + r0 + j)*LSTR + n*16 + c0]);
}

__device__ __forceinline__ void acc_init_glb_w(f32x4 acc[4],
                                               const short* __restrict__ src,
                                               const int lane, const int woff)
{
    const int r0 = (lane >> 4) * 4;
    const int c0 = lane & 15;
#pragma unroll
    for (int n = 0; n < 4; ++n)
#pragma unroll
        for (int j = 0; j < 4; ++j)
            acc[n][j] = bf2f(src[(woff + r0 + j)*64 + n*16 + c0]);
}

// ---------------------------------------------------------------------------
// Scan pass 1, WY form, 4 waves/block, merged P1/P2 phases (round-13 best).
// ---------------------------------------------------------------------------
__global__ __launch_bounds__(256)
void scan_pass1_wy(const float* __restrict__ d, const float* __restrict__ k,
                   const float* __restrict__ v, const float* __restrict__ kk,
                   const float* __restrict__ bb,
                   float* __restrict__ Gbuf, float* __restrict__ Hbuf,
                   short* __restrict__ Yg, short* __restrict__ Ug)
{
    __shared__ short L[8*64*LSTR];
    __shared__ float wprod[4][64];
    __shared__ float cTl[64];
    short* A_  = L + 0*64*LSTR;  // Ah; later XiT
    short* B_  = L + 1*64*LSTR;  // Bh; later XjT
    short* K_  = L + 2*64*LSTR;  // Kh; later Cb
    short* V_  = L + 3*64*LSTR;  // Vt
    short* BT_ = L + 4*64*LSTR;  // BhT
    short* KT_ = L + 5*64*LSTR;  // KhT
    short* N_  = L + 6*64*LSTR;  // Nb
    short* NT_ = L + 7*64*LSTR;  // Nt

    const int chunk = blockIdx.x;
    const int bh = blockIdx.y;
    const int b = bh >> 4, h = bh & 15;
    const int tid = threadIdx.x;
    const int w = tid >> 6;
    const int lane = tid & 63;
    const int woff = w * 16;

    const size_t base = ((size_t)b*TSEQ + (size_t)chunk*CHUNK + woff)*CDIM + h*HSZ + lane;
    float lc[16];
    float s = 1.f;
#pragma unroll
    for (int t = 0; t < 16; ++t) { s *= d[base + (size_t)t*CDIM]; lc[t] = s; }
    wprod[w][lane] = s;
    __syncthreads();
    float pre = 1.f;
#pragma unroll
    for (int w2 = 0; w2 < 3; ++w2) if (w2 < w) pre *= wprod[w2][lane];
    if (w == 3) cTl[lane] = pre * s;

#pragma unroll
    for (int t = 0; t < 16; ++t) {
        const int tg = woff + t;
        const size_t off = base + (size_t)t*CDIM;
        const float run   = pre * lc[t];
        const float cprev = (t == 0) ? pre : (pre * lc[t-1]);
        const float ern   = 1.f / run;
        A_[tg*LSTR + lane] = to_bf16(-kk[off] * cprev);
        const short bv = to_bf16(bb[off] * ern);
        B_[tg*LSTR + lane] = bv;  BT_[lane*LSTR + tg] = bv;
        const short kv = to_bf16(k[off] * ern);
        K_[tg*LSTR + lane] = kv;  KT_[lane*LSTR + tg] = kv;
        V_[lane*LSTR + tg] = to_bf16(v[off]);
    }
    __syncthreads();

    f32x4 xj[4], xi[4], tmpN[4], tmpC[4];

    // Phase 1 (merged): N = stril(A B^T), C = stril(A K^T), xj = A rows
    zero4(tmpN);  mm_nt_w(A_, B_, tmpN, lane, woff);
    zero4(tmpC);  mm_nt_w(A_, K_, tmpC, lane, woff);
    acc_init_lds_w(xj, A_, lane, woff);
    __syncthreads();                       // reads of A_,B_,K_ complete
    acc_store_w<1, true, true >(tmpN, N_, NT_, lane, woff);
    acc_store_w<1, true, false>(tmpC, K_, nullptr, lane, woff);   // C -> K-space
    acc_store_w<0, false, true>(xj, nullptr, B_, lane, woff);     // XjT -> B-space
    __syncthreads();

    // Phase 2: xi = C V; XiT -> A-space (A_ not read this phase)
    zero4(xi);  mm_nt_w(K_, V_, xi, lane, woff);
    acc_store_w<0, false, true>(xi, nullptr, A_, lane, woff);
    __syncthreads();

    // Neumann doubling (exact: N^64 = 0)
#pragma unroll 1
    for (int rd = 0; rd < 6; ++rd) {
        mm_nt_w(N_, B_, xj, lane, woff);
        mm_nt_w(N_, A_, xi, lane, woff);
        if (rd < 5) { zero4(tmpN); mm_nt_w(N_, NT_, tmpN, lane, woff); }
        __syncthreads();
        acc_store_w<0, false, true>(xj, nullptr, B_, lane, woff);
        acc_store_w<0, false, true>(xi, nullptr, A_, lane, woff);
        if (rd < 5) acc_store_w<0, true, true>(tmpN, N_, NT_, lane, woff);
        __syncthreads();
    }

    const size_t mb = ((size_t)bh*NCHUNK + chunk)*HSZ*HSZ;
    const int r0 = (lane >> 4) * 4;
    const int c0 = lane & 15;

#pragma unroll
    for (int n = 0; n < 4; ++n)
#pragma unroll
        for (int j = 0; j < 4; ++j) {
            const int row = woff + r0 + j;
            const int col = n*16 + c0;
            Yg[mb + row*64 + col] = to_bf16(xj[n][j]);
            Ug[mb + row*64 + col] = to_bf16(xi[n][j]);
        }

    float ctv[4];
#pragma unroll
    for (int n = 0; n < 4; ++n) ctv[n] = cTl[n*16 + c0];

    zero4(tmpN);  mm_nt_w(B_, BT_, tmpN, lane, woff);
#pragma unroll
    for (int n = 0; n < 4; ++n)
#pragma unroll
        for (int j = 0; j < 4; ++j) {
            const int row = woff + r0 + j;
            const int col = n*16 + c0;
            const float id = (row == col) ? 1.f : 0.f;
            Gbuf[mb + (size_t)row*HSZ + col] = (tmpN[n][j] + id) * ctv[n];
        }

    zero4(tmpN);
    mm_nt_w(A_, BT_, tmpN, lane, woff);
    mm_nt_w(V_, KT_, tmpN, lane, woff);
#pragma unroll
    for (int n = 0; n < 4; ++n)
#pragma unroll
        for (int j = 0; j < 4; ++j) {
            const int row = woff + r0 + j;
            const int col = n*16 + c0;
            Hbuf[mb + (size_t)row*HSZ + col] = tmpN[n][j] * ctv[n];
        }
}

// ---------------------------------------------------------------------------
// Scan pass 2 (unchanged, verified)
// ---------------------------------------------------------------------------
__global__ __launch_bounds__(256)
void scan_pass2(const float* __restrict__ Gbuf, const float* __restrict__ Hbuf,
                float* __restrict__ S0buf)
{
    const int rg = blockIdx.x;
    const int bh = blockIdx.y;
    const int tid = threadIdx.x;
    const int il = tid & 15;
    const int q4 = tid >> 4;
    const int row = rg*16 + il;

    __shared__ float Gs[64][68];
    __shared__ float Ssh[16][68];

    float frag[4] = {0.f, 0.f, 0.f, 0.f};
    *(float4*)&Ssh[il][q4*4] = make_float4(0.f, 0.f, 0.f, 0.f);

    for (int c = 0; c < NCHUNK; ++c) {
        const size_t mbase = ((size_t)bh*NCHUNK + c)*HSZ*HSZ;
#pragma unroll
        for (int p = 0; p < 4; ++p) {
            const int f = tid*16 + p*4;
            const int rr = f >> 6, cc = f & 63;
            *(float4*)&Gs[rr][cc] = *(const float4*)(Gbuf + mbase + f);
        }
        *(float4*)(S0buf + mbase + (size_t)row*HSZ + q4*4) =
            make_float4(frag[0], frag[1], frag[2], frag[3]);
        __syncthreads();

        float4 hv = *(const float4*)(Hbuf + mbase + (size_t)row*HSZ + q4*4);
        float a0 = hv.x, a1 = hv.y, a2 = hv.z, a3 = hv.w;
#pragma unroll
        for (int j = 0; j < 64; ++j) {
            const float sj = Ssh[il][j];
            const float4 gv = *(const float4*)&Gs[j][q4*4];
            a0 = fmaf(sj, gv.x, a0);
            a1 = fmaf(sj, gv.y, a1);
            a2 = fmaf(sj, gv.z, a2);
            a3 = fmaf(sj, gv.w, a3);
        }
        __syncthreads();
        frag[0] = a0; frag[1] = a1; frag[2] = a2; frag[3] = a3;
        *(float4*)&Ssh[il][q4*4] = make_float4(a0, a1, a2, a3);
    }
}

// ---------------------------------------------------------------------------
// Scan pass 3 lite, 4 waves/block (round-13 verified)
// ---------------------------------------------------------------------------
__global__ __launch_bounds__(256)
void scan_pass3_lite4(const float* __restrict__ r, const float* __restrict__ d,
                      const float* __restrict__ k, const float* __restrict__ v,
                      const float* __restrict__ bb,
                      const short* __restrict__ Yg, const short* __restrict__ Ug,
                      const float* __restrict__ S0buf, float* __restrict__ y)
{
    __shared__ short L[8*64*LSTR];
    __shared__ float wprod[4][64];
    short* R_  = L + 0*64*LSTR;
    short* B_  = L + 1*64*LSTR;
    short* K_  = L + 2*64*LSTR;
    short* V_  = L + 3*64*LSTR;
    short* Yn  = L + 4*64*LSTR;
    short* Wt  = L + 5*64*LSTR;
    short* P1b = L + 6*64*LSTR;
    short* P2b = L + 7*64*LSTR;

    const int chunk = blockIdx.x;
    const int bh = blockIdx.y;
    const int b = bh >> 4, h = bh & 15;
    const int tid = threadIdx.x;
    const int w = tid >> 6;
    const int lane = tid & 63;
    const int woff = w * 16;
    const size_t mb = ((size_t)bh*NCHUNK + chunk)*HSZ*HSZ;

    const size_t base = ((size_t)b*TSEQ + (size_t)chunk*CHUNK + woff)*CDIM + h*HSZ + lane;
    float lc[16];
    float s = 1.f;
#pragma unroll
    for (int t = 0; t < 16; ++t) { s *= d[base + (size_t)t*CDIM]; lc[t] = s; }
    wprod[w][lane] = s;
    __syncthreads();
    float pre = 1.f;
#pragma unroll
    for (int w2 = 0; w2 < 3; ++w2) if (w2 < w) pre *= wprod[w2][lane];

#pragma unroll
    for (int t = 0; t < 16; ++t) {
        const int tg = woff + t;
        const size_t off = base + (size_t)t*CDIM;
        const float run = pre * lc[t];
        const float ern = 1.f / run;
        R_[tg*LSTR + lane] = to_bf16(r[off] * run);
        B_[tg*LSTR + lane] = to_bf16(bb[off] * ern);
        K_[tg*LSTR + lane] = to_bf16(k[off]  * ern);
        V_[lane*LSTR + tg] = to_bf16(v[off]);
    }
    {
        const int row = woff + (lane & 15);
        const int cb  = (lane >> 4) * 16;
        const short* yp = Yg + mb + (size_t)row*64 + cb;
        *(bf16x8*)&Yn[row*LSTR + cb]     = *(const bf16x8*)yp;
        *(bf16x8*)&Yn[row*LSTR + cb + 8] = *(const bf16x8*)(yp + 8);
    }
    __syncthreads();

    const float* S0g = S0buf + mb;
    f32x4 a4[4], o4[4];

    acc_init_glb_w(a4, Ug + mb, lane, woff);
    mm_nt_gf32_w(Yn, S0g, a4, lane, woff);
    acc_store_w<0, false, true>(a4, nullptr, Wt, lane, woff);

    zero4(a4);  mm_nt_w(R_, B_, a4, lane, woff);
    acc_store_w<2, true, false>(a4, P1b, nullptr, lane, woff);
    zero4(a4);  mm_nt_w(R_, K_, a4, lane, woff);
    acc_store_w<2, true, false>(a4, P2b, nullptr, lane, woff);
    __syncthreads();

    zero4(o4);
    mm_nt_gf32_w(R_, S0g, o4, lane, woff);
    mm_nt_w(P1b, Wt, o4, lane, woff);
    mm_nt_w(P2b, V_, o4, lane, woff);

    const int r0 = (lane >> 4) * 4;
    const int c0 = lane & 15;
    float* yb = y + ((size_t)b*TSEQ + (size_t)chunk*CHUNK)*CDIM + h*HSZ;
#pragma unroll
    for (int n = 0; n < 4; ++n)
#pragma unroll
        for (int j = 0; j < 4; ++j)
            yb[(size_t)(woff + r0 + j)*CDIM + n*16 + c0] = o4[n][j];
}

// ---------------------------------------------------------------------------
// GroupNorm + rank-1 rwkv residual + *g; writes bf16 (y*g) for the Wo GEMM.
// ---------------------------------------------------------------------------
__global__ __launch_bounds__(1024)
void gn_kernel(const float* __restrict__ r, const float* __restrict__ k,
               const float* __restrict__ v, const float* __restrict__ g,
               const float* __restrict__ rk, const float* __restrict__ gamma,
               const float* __restrict__ beta, const float* __restrict__ y,
               short* __restrict__ ybf)
{
    const int m = blockIdx.x;
    const int c = threadIdx.x;
    const size_t o = (size_t)m*CDIM + c;
    const float yv = y[o];
    float s1 = yv, s2 = yv*yv;
#pragma unroll
    for (int mask = 1; mask < 64; mask <<= 1) {
        s1 += __shfl_xor(s1, mask);
        s2 += __shfl_xor(s2, mask);
    }
    const float mu  = s1 * (1.f/HSZ);
    const float var = s2 * (1.f/HSZ) - mu*mu;
    const float gn  = (yv - mu) * rsqrtf(var + 0.00064f) * gamma[c] + beta[c];

    float p = r[o] * k[o] * rk[c];
#pragma unroll
    for (int mask = 1; mask < 64; mask <<= 1) p += __shfl_xor(p, mask);

    ybf[o] = to_bf16((gn + p * v[o]) * g[o]);
}

// ---------------------------------------------------------------------------
extern "C" void kernel_launch(void* const* d_in, const int* in_sizes, int n_in,
                              void* d_out, int out_size, void* d_ws, size_t ws_size,
                              hipStream_t stream)
{
    const float* x      = (const float*)d_in[0];
    const float* vfirst = (const float*)d_in[1];
    const float* x_r = (const float*)d_in[2];
    const float* x_w = (const float*)d_in[3];
    const float* x_k = (const float*)d_in[4];
    const float* x_v = (const float*)d_in[5];
    const float* x_a = (const float*)d_in[6];
    const float* x_g = (const float*)d_in[7];
    const float* w0  = (const float*)d_in[8];
    const float* w1  = (const float*)d_in[9];
    const float* w2  = (const float*)d_in[10];
    const float* a0  = (const float*)d_in[11];
    const float* a1  = (const float*)d_in[12];
    const float* a2  = (const float*)d_in[13];
    const float* v0p = (const float*)d_in[14];
    const float* v1  = (const float*)d_in[15];
    const float* v2  = (const float*)d_in[16];
    const float* g1  = (const float*)d_in[17];
    const float* g2  = (const float*)d_in[18];
    const float* k_k = (const float*)d_in[19];
    const float* k_a = (const float*)d_in[20];
    const float* r_k = (const float*)d_in[21];
    const float* Wr  = (const float*)d_in[22];
    const float* Wk  = (const float*)d_in[23];
    const float* Wv  = (const float*)d_in[24];
    const float* Wo  = (const float*)d_in[25];
    const float* lng = (const float*)d_in[26];
    const float* lnb = (const float*)d_in[27];
    float* outp = (float*)d_out;

    float* ws = (float*)d_ws;
    const size_t BIG = (size_t)MROWS * CDIM;   // 4 Mi floats = 16 MB
    float* rbuf  = ws + 0*BIG;
    float* kbuf  = ws + 1*BIG;
    float* vbuf  = ws + 2*BIG;
    float* dbuf  = ws + 3*BIG;
    float* kkbuf = ws + 4*BIG;
    float* bbuf  = ws + 5*BIG;
    float* gbuf  = ws + 6*BIG;
    float* ybuf  = ws + 7*BIG;
    float* smbuf = ws + 8*BIG;
    short* smA   = (short*)smbuf;
    short* wT    = (short*)(smbuf + (size_t)MROWS*160/2);
    short* Brkv = wT;                                    // [3072][2048]
    short* Bsm  = Brkv + (size_t)3072*K2;                // [288][2048]
    short* WoT  = Bsm  + (size_t)288*K2;                 // [1024][1024]
    short* g2T  = WoT  + (size_t)CDIM*CDIM;              // [1024][128]
    short* axbf = g2T  + (size_t)CDIM*128;               // [4096][2048]
    short* Bsm2 = axbf + (size_t)MROWS*K2;               // [3072][160]

    short* Yg = axbf;
    short* Ug = axbf + (size_t)NBH*NCHUNK*HSZ*HSZ;

    float* twbuf = ybuf;
    float* vvbuf = gbuf;
    float* aabuf = outp;

    float* Gbuf  = ybuf;
    float* Hbuf  = gbuf;
    float* S0buf = outp;
    short* ybf   = (short*)dbuf;
    short* ghbf  = smA + (size_t)MROWS*KS2;

    const dim3 blk(256);

    mix_make<<<dim3(MROWS), blk, 0, stream>>>(x, axbf);
    trans_rkv<<<dim3(32, 32, 3), blk, 0, stream>>>(Wr, Wk, Wv, x_r, x_k, x_v, Brkv);
    trans_sm<<<dim3(4, 32, 4), blk, 0, stream>>>(w1, v1, a1, g1, x_w, x_v, x_a, x_g, Bsm);
    trans_s2<<<dim3(32, 5, 3), blk, 0, stream>>>(w2, v2, a2, Bsm2);
    transpose_cvt<<<dim3(CDIM/32, CDIM/32), blk, 0, stream>>>(Wo, WoT, CDIM, CDIM);
    transpose_cvt<<<dim3(CDIM/32, 128/32),  blk, 0, stream>>>(g2, g2T, 128, CDIM);

    gemm_mfma<128,1,true><<<dim3(3072/128, MROWS/128), blk, 0, stream>>>(
        axbf, Brkv, rbuf, MROWS, 3072, K2, nullptr, nullptr);
    gemm_mfma<32,2,false><<<dim3(288/32, MROWS/128), blk, 0, stream>>>(
        axbf, Bsm, smA, MROWS, 288, K2, nullptr, nullptr);
    gemm_mfma<128,3,false><<<dim3(3072/128, MROWS/128), blk, 0, stream>>>(
        smA, Bsm2, twbuf, MROWS, 3072, KS2, vvbuf, aabuf);

    post_kernel<<<dim3(MROWS), blk, 0, stream>>>(
        twbuf, vvbuf, aabuf, w0, v0p, a0, k_k, k_a, vfirst,
        kbuf, vbuf, dbuf, kkbuf, bbuf);

    scan_pass1_wy<<<dim3(NCHUNK, NBH), blk, 0, stream>>>(
        dbuf, kbuf, vbuf, kkbuf, bbuf, Gbuf, Hbuf, Yg, Ug);
    scan_pass2<<<dim3(4, NBH), blk, 0, stream>>>(Gbuf, Hbuf, S0buf);
    scan_pass3_lite4<<<dim3(NCHUNK, NBH), blk, 0, stream>>>(
        rbuf, dbuf, kbuf, vbuf, bbuf, Yg, Ug, S0buf, ybuf);

    gemm_mfma<128,0,false><<<dim3(CDIM/128, MROWS/128), blk, 0, stream>>>(
        ghbf, g2T, gbuf, MROWS, CDIM, 128, nullptr, nullptr);

    gn_kernel<<<dim3(MROWS), dim3(1024), 0, stream>>>(
        rbuf, kbuf, vbuf, gbuf, r_k, lng, lnb, ybuf, ybf);

    gemm_mfma<128,0,true><<<dim3(CDIM/128, MROWS/128), blk, 0, stream>>>(
        ybf, WoT, outp, MROWS, CDIM, CDIM, nullptr, nullptr);
}